// Round 1
// baseline (228.341 us; speedup 1.0000x reference)
//
#include <hip/hip_runtime.h>
#include <stdint.h>

// LocalContrastiveLoss: exact reproduction of the JAX reference, including
// threefry2x32 PRNG (partitionable mode, the modern JAX default) and
// lax.top_k tie-breaking (lower index wins on equal values).
//
// Shapes: features (B=8, C=256, H=128, W=128) f32; labels (8,128,128) i32.
// Output: single f32 scalar.

namespace {

constexpr int Bb = 8;
constexpr int Nn = 16384;   // H*W
constexpr int NCc = 4;

// ---------------- threefry2x32 (matches jax/_src/prng.py exactly) ----------
__device__ __forceinline__ uint32_t rotl32(uint32_t v, int d) {
  return (v << d) | (v >> (32 - d));
}

__device__ __forceinline__ void threefry2x32(uint32_t k0, uint32_t k1,
                                             uint32_t x0, uint32_t x1,
                                             uint32_t& o0, uint32_t& o1) {
  uint32_t ks2 = k0 ^ k1 ^ 0x1BD11BDAu;
  x0 += k0; x1 += k1;
#define TF_R(d) { x0 += x1; x1 = rotl32(x1, (d)); x1 ^= x0; }
  TF_R(13) TF_R(15) TF_R(26) TF_R(6)
  x0 += k1; x1 += ks2 + 1u;
  TF_R(17) TF_R(29) TF_R(16) TF_R(24)
  x0 += ks2; x1 += k0 + 2u;
  TF_R(13) TF_R(15) TF_R(26) TF_R(6)
  x0 += k0; x1 += k1 + 3u;
  TF_R(17) TF_R(29) TF_R(16) TF_R(24)
  x0 += k1; x1 += ks2 + 4u;
  TF_R(13) TF_R(15) TF_R(26) TF_R(6)
  x0 += ks2; x1 += k0 + 5u;
#undef TF_R
  o0 = x0; o1 = x1;
}

// insert candidate into sorted (descending) top-3 list
__device__ __forceinline__ void ins3(unsigned long long t[3], unsigned long long k) {
  if (k > t[0])      { t[2] = t[1]; t[1] = t[0]; t[0] = k; }
  else if (k > t[1]) { t[2] = t[1]; t[1] = k; }
  else if (k > t[2]) { t[2] = k; }
}

// ---------------- K1: per (key s, image b, class c) top-3 + counts ---------
// Packed rank key: (uniform_float_bits << 32) | (0xFFFFFFFF - pixel_index).
// float bits ((bits>>9)|0x3f800000) are monotone in the uniform value; the
// complemented index reproduces lax.top_k's lower-index-wins tie rule.
__global__ void topk_kernel(const int* __restrict__ labels,
                            int* __restrict__ idx_buf,
                            int* __restrict__ counts) {
  const int g = blockIdx.x;          // 160 = 5*8*4
  const int s = g >> 5;
  const int b = (g >> 2) & 7;
  const int c = g & 3;

  // subkey = jax.random.split(key(42), 5)[s]  (partitionable / fold-like)
  uint32_t sk0, sk1;
  threefry2x32(0u, 42u, 0u, (uint32_t)s, sk0, sk1);

  unsigned long long t[3] = {0ull, 0ull, 0ull};
  int cnt = 0;
  const uint32_t base_j = (uint32_t)((b * NCc + c) * Nn);   // flat (b,c,0) index
  const int* lab_row = labels + b * Nn;
  for (int n = threadIdx.x; n < Nn; n += 256) {
    if (lab_row[n] == c) {
      ++cnt;
      uint32_t r0, r1;
      threefry2x32(sk0, sk1, 0u, base_j + (uint32_t)n, r0, r1);
      uint32_t bits = r0 ^ r1;                 // partitionable 32-bit draw
      uint32_t fb = (bits >> 9) | 0x3f800000u; // uniform float bits, [1,2)
      unsigned long long key = ((unsigned long long)fb << 32) |
                               (unsigned long long)(0xFFFFFFFFu - (uint32_t)n);
      ins3(t, key);
    }
  }

  const int lane = threadIdx.x & 63;
  const int wave = threadIdx.x >> 6;
  for (int off = 32; off > 0; off >>= 1) {
    unsigned long long o0 = __shfl_down(t[0], (unsigned)off);
    unsigned long long o1 = __shfl_down(t[1], (unsigned)off);
    unsigned long long o2 = __shfl_down(t[2], (unsigned)off);
    int oc = __shfl_down(cnt, (unsigned)off);
    ins3(t, o0); ins3(t, o1); ins3(t, o2);
    cnt += oc;
  }
  __shared__ unsigned long long sm[4][3];
  __shared__ int sc[4];
  if (lane == 0) { sm[wave][0] = t[0]; sm[wave][1] = t[1]; sm[wave][2] = t[2]; sc[wave] = cnt; }
  __syncthreads();
  if (threadIdx.x == 0) {
    unsigned long long f[3] = {sm[0][0], sm[0][1], sm[0][2]};
    int tot = sc[0];
    for (int w = 1; w < 4; ++w) {
      ins3(f, sm[w][0]); ins3(f, sm[w][1]); ins3(f, sm[w][2]);
      tot += sc[w];
    }
    for (int r = 0; r < 3; ++r) {
      // empty slot (key==0): index is irrelevant (masked downstream), use 0
      int n = (f[r] == 0ull) ? 0
              : (int)(0xFFFFFFFFu - (uint32_t)(f[r] & 0xFFFFFFFFull));
      idx_buf[g * 3 + r] = n;
    }
    if (s == 0) counts[b * 4 + c] = tot;
  }
}

// ---------------- K2: gather sampled pixels, L2-normalize over channels ----
__global__ void gather_norm_kernel(const float* __restrict__ feat,
                                   const int* __restrict__ idx_buf,
                                   float* __restrict__ fnorm) {
  const int g = blockIdx.x;          // 480 = 5*8*4*3, same layout as idx_buf
  const int b = (g / 12) & 7;
  const int n = idx_buf[g];
  const int ch = threadIdx.x;        // 256 channels
  float v = feat[((b << 8) + ch) * Nn + n];
  float ss = v * v;
  for (int off = 32; off > 0; off >>= 1) ss += __shfl_down(ss, (unsigned)off);
  __shared__ float sr[4];
  __shared__ float snorm;
  const int lane = threadIdx.x & 63, wave = threadIdx.x >> 6;
  if (lane == 0) sr[wave] = ss;
  __syncthreads();
  if (threadIdx.x == 0) snorm = fmaxf(sqrtf(sr[0] + sr[1] + sr[2] + sr[3]), 1e-12f);
  __syncthreads();
  fnorm[g * 256 + ch] = v / snorm;
}

// ---------------- K3: mu = unit(mean of 3 sampled unit vectors) ------------
// m=0: from sample s=0 (part-1 mu1). m=1: from sample s=3 (part-2 mu2).
__global__ void mu_kernel(const float* __restrict__ fnorm, float* __restrict__ mu) {
  const int g = blockIdx.x;          // 64 = 2*8*4: m*32 + b*4 + c
  const int m = g >> 5;
  const int bc = g & 31;
  const int s = m ? 3 : 0;
  const int base = (s * 32 + bc) * 3 * 256;
  const int ch = threadIdx.x;
  float v = (fnorm[base + ch] + fnorm[base + 256 + ch] + fnorm[base + 512 + ch]) / 3.0f;
  float ss = v * v;
  for (int off = 32; off > 0; off >>= 1) ss += __shfl_down(ss, (unsigned)off);
  __shared__ float sr[4];
  __shared__ float snorm;
  const int lane = threadIdx.x & 63, wave = threadIdx.x >> 6;
  if (lane == 0) sr[wave] = ss;
  __syncthreads();
  if (threadIdx.x == 0) snorm = fmaxf(sqrtf(sr[0] + sr[1] + sr[2] + sr[3]), 1e-8f);
  __syncthreads();
  mu[g * 256 + ch] = v / snorm;
}

// ---------------- K4: per-anchor (b,c,p) loss terms ------------------------
__global__ void loss_kernel(const float* __restrict__ fnorm,
                            const float* __restrict__ mu,
                            const int* __restrict__ counts,
                            float* __restrict__ partials) {
  const int g = blockIdx.x;          // 96 = 8*4*3
  const int b = g / 12;
  const int c = (g % 12) / 3;
  const int p = g % 3;
  const int ch = threadIdx.x;
  const int bc = b * 4 + c;

  const float a1 = fnorm[(bc * 3 + p) * 256 + ch];           // s=0 anchor
  const float a2 = fnorm[((64 + bc) * 3 + p) * 256 + ch];    // s=2 anchor

  float part[33];
  // [0] dot(a1, mu1[b,c])
  part[0] = a1 * mu[bc * 256 + ch];
  // [1..12] dot(a1, neg1[b,e,k])   (s=1)
#pragma unroll
  for (int e = 0; e < 4; ++e)
#pragma unroll
    for (int k = 0; k < 3; ++k)
      part[1 + e * 3 + k] = a1 * fnorm[((32 + b * 4 + e) * 3 + k) * 256 + ch];
  // [13..20] dot(a2, mu2[b2,c])
#pragma unroll
  for (int b2 = 0; b2 < 8; ++b2)
    part[13 + b2] = a2 * mu[(32 + b2 * 4 + c) * 256 + ch];
  // [21..32] dot(a2, neg2[b,e,k])  (s=4)
#pragma unroll
  for (int e = 0; e < 4; ++e)
#pragma unroll
    for (int k = 0; k < 3; ++k)
      part[21 + e * 3 + k] = a2 * fnorm[((128 + b * 4 + e) * 3 + k) * 256 + ch];

  for (int off = 32; off > 0; off >>= 1) {
#pragma unroll
    for (int i = 0; i < 33; ++i) part[i] += __shfl_down(part[i], (unsigned)off);
  }
  __shared__ float red[4][33];
  const int lane = threadIdx.x & 63, wave = threadIdx.x >> 6;
  if (lane == 0) {
#pragma unroll
    for (int i = 0; i < 33; ++i) red[wave][i] = part[i];
  }
  __syncthreads();

  if (threadIdx.x == 0) {
    float d[33];
#pragma unroll
    for (int i = 0; i < 33; ++i) d[i] = red[0][i] + red[1][i] + red[2][i] + red[3][i];

    int cb[4];
    for (int e = 0; e < 4; ++e) cb[e] = counts[b * 4 + e];
    bool has_neg = false;
    for (int e = 0; e < 4; ++e) if (e != c && cb[e] > 0) has_neg = true;
    const bool valid_anchor = (cb[c] >= 3) && has_neg;

    float sn1 = 0.f, sn2 = 0.f;
    for (int e = 0; e < 4; ++e) {
      if (e == c) continue;
      int km = cb[e] < 3 ? cb[e] : 3;
      for (int k = 0; k < km; ++k) {
        sn1 += expf(d[1 + e * 3 + k] * 10.0f);
        sn2 += expf(d[21 + e * 3 + k] * 10.0f);
      }
    }
    float term = 0.f;
    if (valid_anchor) {
      float sp1 = expf(d[0] * 10.0f);
      term -= logf(sp1 / (sp1 + sn1 + 1e-8f));
      for (int b2 = 0; b2 < 8; ++b2) {
        if (b2 == b) continue;
        if (counts[b2 * 4 + c] >= 3) {
          float sp2 = expf(d[13 + b2] * 10.0f);
          term -= logf(sp2 / (sp2 + sn2 + 1e-8f));
        }
      }
    }
    partials[g] = term;
  }
}

// ---------------- K5: final reduce + scale ---------------------------------
__global__ void finalize_kernel(const float* __restrict__ partials,
                                float* __restrict__ out) {
  const int t = threadIdx.x;         // 128 threads
  float v = (t < 96) ? partials[t] : 0.f;
  for (int off = 32; off > 0; off >>= 1) v += __shfl_down(v, (unsigned)off);
  __shared__ float s2[2];
  if ((t & 63) == 0) s2[t >> 6] = v;
  __syncthreads();
  if (t == 0) {
    double total = (double)s2[0] + (double)s2[1];
    out[0] = (float)(0.1 * total / (24.0 + 1e-8));  // LAM*loss/(B*P+EPS)
  }
}

}  // namespace

extern "C" void kernel_launch(void* const* d_in, const int* in_sizes, int n_in,
                              void* d_out, int out_size, void* d_ws, size_t ws_size,
                              hipStream_t stream) {
  const float* feat = (const float*)d_in[0];
  const int* labels = (const int*)d_in[1];
  float* out = (float*)d_out;
  char* ws = (char*)d_ws;

  // workspace layout (bytes):
  //   [0, 1920)            idx_buf: 5*8*4*3 int32 sampled pixel indices
  //   [1920, 2048)         counts : 8*4 int32 class counts
  //   [2048, 493568)       fnorm  : 480*256 f32 normalized sampled vectors
  //   [493568, 559104)     mu     : 2*32*256 f32 unit means
  //   [559104, 559488)     partials: 96 f32 per-anchor loss terms
  int* idx_buf   = (int*)(ws);
  int* counts    = (int*)(ws + 1920);
  float* fnorm   = (float*)(ws + 2048);
  float* mu      = (float*)(ws + 493568);
  float* partials= (float*)(ws + 559104);

  topk_kernel<<<160, 256, 0, stream>>>(labels, idx_buf, counts);
  gather_norm_kernel<<<480, 256, 0, stream>>>(feat, idx_buf, fnorm);
  mu_kernel<<<64, 256, 0, stream>>>(fnorm, mu);
  loss_kernel<<<96, 256, 0, stream>>>(fnorm, mu, counts, partials);
  finalize_kernel<<<1, 128, 0, stream>>>(partials, out);
}